// Round 6
// baseline (5965.092 us; speedup 1.0000x reference)
//
#include <hip/hip_runtime.h>
#include <stdint.h>

#define B_ 4
#define T_ 4096
#define D_ 1024
#define H_ 16
#define HD_ 64
#define C_ 64
#define N_ 64
#define BT_ (B_*T_)

typedef unsigned short u16;
typedef __attribute__((ext_vector_type(8))) short bf16x8;
typedef __attribute__((ext_vector_type(4))) float f32x4;

__device__ __forceinline__ u16 f2b(float f){
  uint32_t x = __float_as_uint(f);
  uint32_t r = x + 0x7FFFu + ((x>>16)&1u);
  return (u16)(r>>16);
}
__device__ __forceinline__ ushort4 f2b4(float4 v){
  ushort4 r; r.x=f2b(v.x); r.y=f2b(v.y); r.z=f2b(v.z); r.w=f2b(v.w); return r;
}
__device__ __forceinline__ float wave_sum(float v){
  #pragma unroll
  for(int off=32; off>0; off>>=1) v += __shfl_down(v, off);
  return __shfl(v, 0);
}

// ---------------------------------------------------------------------------
// K0: weight prep: Bt[n][k] = bf16(B[k][n]), 1024x1024
// ---------------------------------------------------------------------------
__global__ __launch_bounds__(256) void k_prep(const float* __restrict__ Bsrc,
    u16* __restrict__ Bt){
  __shared__ float tile[64][65];
  int n0 = blockIdx.x*64, k0 = blockIdx.y*64;
  int tid = threadIdx.x;
  #pragma unroll
  for(int j=0;j<4;++j){
    int idx = tid+256*j; int k = idx>>4, n4 = (idx&15)*4;
    float4 v = *(const float4*)(Bsrc + (size_t)(k0+k)*D_ + n0+n4);
    tile[k][n4]=v.x; tile[k][n4+1]=v.y; tile[k][n4+2]=v.z; tile[k][n4+3]=v.w;
  }
  __syncthreads();
  #pragma unroll
  for(int j=0;j<4;++j){
    int idx = tid+256*j; int n = idx>>4, k4 = (idx&15)*4;
    ushort4 o;
    o.x=f2b(tile[k4+0][n]); o.y=f2b(tile[k4+1][n]);
    o.z=f2b(tile[k4+2][n]); o.w=f2b(tile[k4+3][n]);
    *(ushort4*)(Bt + (size_t)(n0+n)*D_ + k0+k4) = o;
  }
}

// ---------------------------------------------------------------------------
// K1: per-(b,t): invn = 1/||x_head||, gate/beta/decay projections
// ---------------------------------------------------------------------------
__global__ __launch_bounds__(256) void k_small(const float* __restrict__ x,
    const float* __restrict__ wg, const float* __restrict__ wb, const float* __restrict__ wa,
    const float* __restrict__ dtb, const float* __restrict__ alog,
    float* __restrict__ invn, float* __restrict__ gate, float* __restrict__ beta,
    float* __restrict__ dec){
  int row = blockIdx.x;            // b*T + t
  __shared__ float xs[D_];
  {
    int i0 = threadIdx.x*4;
    float4 u = *(const float4*)(x + (size_t)row*D_ + i0);
    xs[i0+0]=u.x; xs[i0+1]=u.y; xs[i0+2]=u.z; xs[i0+3]=u.w;
  }
  __syncthreads();
  int w = threadIdx.x>>6, l = threadIdx.x&63;
  #pragma unroll
  for(int i=0;i<4;++i){
    int h = w*4+i;
    float v = xs[h*64+l];
    float ss = wave_sum(v*v);
    float dg=0.f,db=0.f,da=0.f;
    #pragma unroll
    for(int k16=0;k16<16;++k16){
      int k = l + 64*k16;
      float xv = xs[k];
      dg += xv*wg[k*H_+h];
      db += xv*wb[k*H_+h];
      da += xv*wa[k*H_+h];
    }
    dg = wave_sum(dg); db = wave_sum(db); da = wave_sum(da);
    if(l==0){
      int o = row*H_+h;
      invn[o] = 1.f/fmaxf(sqrtf(ss),1e-12f);
      gate[o] = 1.f/(1.f+expf(-dg));
      beta[o] = 1.f/(1.f+expf(-db));
      float z = da + dtb[h];
      float sp = (z>20.f)? z : log1pf(expf(z));
      dec[o] = -expf(alog[h])*sp;
    }
  }
}

// ---------------------------------------------------------------------------
// K2: MFMA GEMM: Co(f32 MxN) = A(f32 MxK) @ Bt(bf16 [n][k]) [+ resid]
// M=16384, N=K=1024. 128x128 tile, BK=32, 4 waves (2x2), 16x16x32 bf16 MFMA.
// A-frag: A[m=lane&15][k=8*(lane>>4)+j]; B-frag: B[k=8*(lane>>4)+j][n=lane&15]
// C/D: col=lane&15, row=4*(lane>>4)+reg   (verified m89/m91)
// ---------------------------------------------------------------------------
__global__ __launch_bounds__(256) void k_mm(const float* __restrict__ A,
    const u16* __restrict__ Bt, const float* __restrict__ resid,
    float* __restrict__ Co, int addres){
  __shared__ __align__(16) u16 As[128*40];   // [m][k], row stride 40
  __shared__ __align__(16) u16 Bs[128*40];   // [n][k], row stride 40
  int tid = threadIdx.x; int w = tid>>6, lane = tid&63;
  int m0 = blockIdx.y*128, n0 = blockIdx.x*128;
  int wr = w>>1, wc = w&1;
  int mrow = lane&15, q = lane>>4;
  f32x4 acc[4][4] = {};
  for(int k0=0;k0<D_;k0+=32){
    float4 av[4]; uint4 bv[2];
    #pragma unroll
    for(int j=0;j<4;++j){
      int idx = tid+256*j; int m = idx>>3, kq = idx&7;
      av[j] = *(const float4*)(A + (size_t)(m0+m)*D_ + k0 + kq*4);
    }
    #pragma unroll
    for(int j=0;j<2;++j){
      int idx = tid+256*j; int nn = idx>>2, kq = idx&3;
      bv[j] = *(const uint4*)(Bt + (size_t)(n0+nn)*D_ + k0 + kq*8);
    }
    __syncthreads();
    #pragma unroll
    for(int j=0;j<4;++j){
      int idx = tid+256*j; int m = idx>>3, kq = idx&7;
      *(ushort4*)(As + m*40 + kq*4) = f2b4(av[j]);
    }
    #pragma unroll
    for(int j=0;j<2;++j){
      int idx = tid+256*j; int nn = idx>>2, kq = idx&3;
      *(uint4*)(Bs + nn*40 + kq*8) = bv[j];
    }
    __syncthreads();
    bf16x8 af[4], bfr[4];
    #pragma unroll
    for(int t4=0;t4<4;++t4){
      af[t4]  = *(const bf16x8*)(As + (wr*64 + t4*16 + mrow)*40 + q*8);
      bfr[t4] = *(const bf16x8*)(Bs + (wc*64 + t4*16 + mrow)*40 + q*8);
    }
    #pragma unroll
    for(int ti=0;ti<4;++ti)
      #pragma unroll
      for(int tj=0;tj<4;++tj)
        acc[ti][tj] = __builtin_amdgcn_mfma_f32_16x16x32_bf16(af[ti], bfr[tj], acc[ti][tj], 0,0,0);
  }
  #pragma unroll
  for(int ti=0;ti<4;++ti){
    #pragma unroll
    for(int tj=0;tj<4;++tj){
      #pragma unroll
      for(int r=0;r<4;++r){
        int row = m0 + wr*64 + ti*16 + q*4 + r;
        int cc  = n0 + wc*64 + tj*16 + mrow;
        size_t off = (size_t)row*D_ + cc;
        float val = acc[ti][tj][r];
        if(addres) val += resid[off];
        Co[off] = val;
      }
    }
  }
}

// ---------------------------------------------------------------------------
// K3: per-chunk: cum, KK, forward substitution -> v_corr (in-place), wk_cd
// ---------------------------------------------------------------------------
__global__ __launch_bounds__(256) void k_chunk(const float* __restrict__ x,
    const float* __restrict__ invn, const float* __restrict__ beta_g,
    const float* __restrict__ dec_g, float* __restrict__ cum_g,
    float* __restrict__ vbuf, float* __restrict__ wkop){
  int bid = blockIdx.x;                  // b*H*N + h*N + n
  int n = bid & 63; int h = (bid>>6) & 15; int b = bid>>10;
  int t0 = n*C_;
  __shared__ float sm[12608];
  float* WK = sm;            // 64*65 (padded), aliased by XV later
  float* KK = sm+4160;       // 64*64
  float* XW = sm+8256;       // 64*64
  float* BS = sm+12352;      // 64
  float* CU = sm+12416;      // 64
  float* DE = sm+12480;      // 64
  float* GS = sm+12544;      // 64
  float* XV = WK;            // 4096 over WK region (stride 64)
  int tid = threadIdx.x, w = tid>>6, l = tid&63;
  #pragma unroll
  for(int it=0; it<16; ++it){
    int idx = tid + 256*it; int c = idx>>6, dd = idx&63;
    int tw = t0+c-1;
    float wv = 0.f;
    if(tw>=0){
      size_t rr = (size_t)(b*T_+tw);
      wv = x[rr*D_ + h*64 + dd] * invn[rr*H_ + h];
    }
    WK[c*65+dd] = wv;
  }
  if(tid<64){
    size_t rr = (size_t)(b*T_+t0+tid);
    BS[tid] = beta_g[rr*H_+h];
    GS[tid] = dec_g[rr*H_+h];
  }
  __syncthreads();
  if(w==0){
    float xg = GS[l];
    #pragma unroll
    for(int off=1; off<64; off<<=1){
      float y = __shfl_up(xg, off);
      if(l>=off) xg += y;
    }
    CU[l]=xg; DE[l]=expf(xg);
    cum_g[(size_t)bid*64 + l] = xg;
  }
  __syncthreads();
  float wkj[64];
  #pragma unroll
  for(int dd=0; dd<64; ++dd) wkj[dd] = WK[l*65+dd];
  #pragma unroll 1
  for(int it=0; it<16; ++it){
    int i = w + 4*it;
    float aw=0.f;
    #pragma unroll
    for(int dd=0; dd<64; ++dd) aw += WK[i*65+dd]*wkj[dd];
    KK[i*64+l] = (l<i) ? (BS[i]*aw*expf(CU[i]-CU[l])) : 0.f;
  }
  __syncthreads();
  float rv[16], rw[16];
  #pragma unroll
  for(int it=0; it<16; ++it){
    int i = w + 4*it;
    rw[it] = WK[i*65+l]*BS[i]*DE[i];
    rv[it] = vbuf[(size_t)(b*T_+t0+i)*D_ + h*64 + l]*BS[i];
  }
  __syncthreads();
  #pragma unroll
  for(int it=0; it<16; ++it){
    int i = w + 4*it;
    XV[i*64+l] = rv[it];
    XW[i*64+l] = rw[it];
  }
  __syncthreads();
  if(w<2){
    float* Xc = (w==0) ? XV : XW;
    for(int i=1;i<64;++i){
      float acc = Xc[i*64+l];
      for(int k=0;k<i;++k) acc -= KK[i*64+k]*Xc[k*64+l];
      Xc[i*64+l] = acc;
    }
  }
  __syncthreads();
  #pragma unroll
  for(int it=0; it<16; ++it){
    int i = w + 4*it;
    vbuf[(size_t)(b*T_+t0+i)*D_ + h*64 + l] = XV[i*64+l];
    wkop[(size_t)bid*4096 + i*64 + l]       = XW[i*64+l];
  }
}

// ---------------------------------------------------------------------------
// K4 v3: scan per (b,h), 1024 threads (16 waves x 4 rows), reg prefetch
// ---------------------------------------------------------------------------
__global__ __launch_bounds__(1024) void k_scan(const float* __restrict__ x,
    const float* __restrict__ invn_g, const float* __restrict__ cum_g,
    float* __restrict__ vbuf, float* __restrict__ wkop){
  int bh = blockIdx.x;  // b*H + h
  int b = bh>>4, h = bh&15;
  __shared__ float sm[12576];
  float* S   = sm;          // 64x64 state
  float* WCD = sm+4096;     // wkcd chunk; later VNS (= v_new * DW)
  float* RK  = sm+8192;     // rk chunk (pre-scaled by invn)
  float* CU  = sm+12288;    // 64
  float* DW  = sm+12352;    // 64
  float* DEc = sm+12416;    // 64
  float* PREV= sm+12480;    // 64
  float* P   = sm+12544;    // 16 (+pad)
  int tid = threadIdx.x, w = tid>>6, l = tid&63;

  #pragma unroll
  for(int it=0;it<4;++it) S[tid+1024*it]=0.f;
  if(tid<64) PREV[tid]=0.f;

  // prologue: prefetch chunk 0
  float4 pW, pR;
  float pV[4], pIv, pC=0.f;
  {
    size_t base0 = (size_t)bh*N_*4096;
    pW = *(const float4*)(wkop + base0 + (size_t)tid*4);
    int c = tid>>4, c4 = (tid&15)*4;
    pR = *(const float4*)(x + (size_t)(b*T_+c)*D_ + h*64 + c4);
    pIv = invn_g[(size_t)(b*T_+(tid>>4))*H_ + h];
    #pragma unroll
    for(int it=0;it<4;++it){
      int cc = 4*w+it;
      pV[it] = vbuf[(size_t)(b*T_+cc)*D_ + h*64 + l];
    }
    if(tid<64) pC = cum_g[(size_t)bh*N_*64 + tid];
  }
  __syncthreads();

  for(int n=0;n<N_;++n){
    int t0 = n*C_;
    size_t base = ((size_t)bh*N_ + n)*4096;
    // stage
    *(float4*)(WCD + tid*4) = pW;
    {
      float4 r = pR;
      r.x*=pIv; r.y*=pIv; r.z*=pIv; r.w*=pIv;
      *(float4*)(RK + tid*4) = r;
    }
    if(tid<64){
      CU[tid] = pC;
      float last = __shfl(pC, 63);
      DW[tid]  = expf(last - pC);
      DEc[tid] = expf(pC);
    }
    __syncthreads();
    float elast = expf(CU[63]);
    float vn[4];
    #pragma unroll
    for(int it=0;it<4;++it) vn[it]=pV[it];
    // s_col = column l of S_pre
    float s_col[64];
    #pragma unroll
    for(int k=0;k<64;++k) s_col[k]=S[k*64+l];
    // prefetch chunk n+1
    if(n+1 < N_){
      int t1 = t0 + C_;
      size_t base1 = base + 4096;
      pW = *(const float4*)(wkop + base1 + (size_t)tid*4);
      int c = tid>>4, c4=(tid&15)*4;
      pR = *(const float4*)(x + (size_t)(b*T_+t1+c)*D_ + h*64 + c4);
      pIv = invn_g[(size_t)(b*T_+t1+(tid>>4))*H_ + h];
      #pragma unroll
      for(int it=0;it<4;++it){
        int cc = 4*w+it;
        pV[it] = vbuf[(size_t)(b*T_+t1+cc)*D_ + h*64 + l];
      }
      if(tid<64) pC = cum_g[((size_t)bh*N_+n+1)*64 + tid];
    }
    // v_new = v_corr - wkcd @ S_pre ; opart = exp(cum)*(rk @ S_pre)
    #pragma unroll 1
    for(int it=0;it<4;++it){
      int c = 4*w+it;
      float a = vn[it], o = 0.f;
      #pragma unroll
      for(int d4=0;d4<16;++d4){
        float4 wv = *(const float4*)&WCD[c*64+4*d4];
        float4 rv = *(const float4*)&RK [c*64+4*d4];
        a -= wv.x*s_col[4*d4]+wv.y*s_col[4*d4+1]+wv.z*s_col[4*d4+2]+wv.w*s_col[4*d4+3];
        o += rv.x*s_col[4*d4]+rv.y*s_col[4*d4+1]+rv.z*s_col[4*d4+2]+rv.w*s_col[4*d4+3];
      }
      vn[it]=a;
      vbuf[(size_t)(b*T_+t0+c)*D_ + h*64 + l] = a;
      wkop[base + c*64 + l] = DEc[c]*o;
    }
    __syncthreads();   // all reads of WCD done
    #pragma unroll
    for(int it=0;it<4;++it){
      int c = 4*w+it;
      WCD[c*64+l] = vn[it]*DW[c];
    }
    __syncthreads();
    // S update
    float vns_col[64];
    #pragma unroll
    for(int c=0;c<64;++c) vns_col[c]=WCD[c*64+l];
    float sn[4];
    #pragma unroll
    for(int it=0;it<4;++it){
      int r = 4*w+it;
      sn[it] = elast*S[r*64+l] + PREV[r]*vns_col[0];
    }
    #pragma unroll 1
    for(int c=1;c<64;++c){
      float4 rseg = *(const float4*)&RK[(c-1)*64 + 4*w];   // wk[c] = rk[c-1]
      float vc = vns_col[c];
      sn[0] += rseg.x*vc; sn[1] += rseg.y*vc;
      sn[2] += rseg.z*vc; sn[3] += rseg.w*vc;
    }
    float p = sn[0]*sn[0]+sn[1]*sn[1]+sn[2]*sn[2]+sn[3]*sn[3];
    p = wave_sum(p);
    if(l==0) P[w]=p;
    __syncthreads();
    float tot = 0.f;
    #pragma unroll
    for(int i=0;i<16;++i) tot += P[i];
    float nrm = sqrtf(tot);
    float scale = fminf(nrm,100.f)/fmaxf(nrm,1e-6f);
    #pragma unroll
    for(int it=0;it<4;++it){
      int r = 4*w+it;
      S[r*64+l] = sn[it]*scale;
    }
    if(tid<64) PREV[tid] = RK[63*64+tid];
    __syncthreads();
  }
}

// ---------------------------------------------------------------------------
// K5: o = gate*(opart + intra @ v_new); intra recomputed; o in-place
// ---------------------------------------------------------------------------
__global__ __launch_bounds__(256) void k_o(const float* __restrict__ x,
    const float* __restrict__ invn, const float* __restrict__ cum_g,
    const float* __restrict__ wkop, const float* __restrict__ gate_g,
    float* __restrict__ vbuf){
  int bid = blockIdx.x; int n = bid&63, h=(bid>>6)&15, b=bid>>10;
  int t0 = n*C_;
  __shared__ float sm[8256];
  float* RK = sm;
  float* VN = sm+4096;
  float* CU = sm+8192;
  float* INT = RK;
  int tid=threadIdx.x, w=tid>>6, l=tid&63;
  if(tid<64) CU[tid] = cum_g[(size_t)bid*64 + tid];
  #pragma unroll 1
  for(int it=0;it<16;++it){
    int idx = tid+256*it; int c=idx>>6, dd=idx&63;
    size_t rr = (size_t)(b*T_+t0+c);
    RK[c*64+dd] = x[rr*D_ + h*64 + dd] * invn[rr*H_ + h];
    VN[idx]     = vbuf[rr*D_ + h*64 + dd];
  }
  __syncthreads();
  float wkj[64];
  {
    int tw = t0+l-1;
    if(tw>=0){
      size_t r2 = (size_t)(b*T_+tw);
      float iv = invn[r2*H_ + h];
      #pragma unroll
      for(int d4=0; d4<16; ++d4){
        float4 u = *(const float4*)(x + r2*D_ + h*64 + 4*d4);
        wkj[4*d4+0]=u.x*iv; wkj[4*d4+1]=u.y*iv;
        wkj[4*d4+2]=u.z*iv; wkj[4*d4+3]=u.w*iv;
      }
    } else {
      #pragma unroll
      for(int dd=0;dd<64;++dd) wkj[dd]=0.f;
    }
  }
  #pragma unroll 1
  for(int it=0;it<16;++it){
    int i = w + 4*it;
    float ar = 0.f;
    #pragma unroll
    for(int d4=0; d4<16; ++d4){
      float4 r4 = *(const float4*)&RK[i*64 + 4*d4];
      ar += r4.x*wkj[4*d4] + r4.y*wkj[4*d4+1] + r4.z*wkj[4*d4+2] + r4.w*wkj[4*d4+3];
    }
    float val = (l<=i) ? (ar*expf(CU[i]-CU[l])) : 0.f;
    INT[i*64+l] = val;
  }
  __syncthreads();
  float vn_col[64];
  #pragma unroll
  for(int k=0;k<64;++k) vn_col[k] = VN[k*64+l];
  #pragma unroll 1
  for(int it=0;it<16;++it){
    int c = w+4*it;
    float acc = 0.f;
    #pragma unroll
    for(int d4=0; d4<16; ++d4){
      float4 i4 = *(const float4*)&INT[c*64 + 4*d4];
      acc += i4.x*vn_col[4*d4] + i4.y*vn_col[4*d4+1] + i4.z*vn_col[4*d4+2] + i4.w*vn_col[4*d4+3];
    }
    size_t rr = (size_t)(b*T_+t0+c);
    float g  = gate_g[rr*H_ + h];
    float op = wkop[(size_t)bid*4096 + c*64 + l];
    vbuf[rr*D_ + h*64 + l] = (op + acc)*g;
  }
}

// ---------------------------------------------------------------------------
extern "C" void kernel_launch(void* const* d_in, const int* in_sizes, int n_in,
                              void* d_out, int out_size, void* d_ws, size_t ws_size,
                              hipStream_t stream) {
  const float* x       = (const float*)d_in[0];
  const float* w_write = (const float*)d_in[1];
  const float* w_gate  = (const float*)d_in[2];
  const float* w_out   = (const float*)d_in[3];
  const float* w_beta  = (const float*)d_in[4];
  const float* w_alpha = (const float*)d_in[5];
  const float* dt_bias = (const float*)d_in[6];
  const float* A_log   = (const float*)d_in[7];
  float* outp = (float*)d_out;

  const size_t big   = (size_t)BT_*D_;
  const size_t small = (size_t)BT_*H_;
  const size_t need  = (2*big + 5*small)*sizeof(float) + 4u*1024*1024;
  if(ws_size < need) return;

  float* ws   = (float*)d_ws;
  float* vbuf = ws;              // v -> v_corr -> v_new -> o
  float* wkop = vbuf + big;      // wk_cd -> opart
  float* invn = wkop + big;
  float* gate = invn + small;
  float* beta = gate + small;
  float* dec  = beta + small;
  float* cum  = dec  + small;
  u16*   btw  = (u16*)(cum + small);
  u16*   bto  = btw + (size_t)D_*D_;

  k_prep<<<dim3(16,16), dim3(256), 0, stream>>>(w_write, btw);
  k_prep<<<dim3(16,16), dim3(256), 0, stream>>>(w_out,  bto);
  k_small<<<dim3(BT_), dim3(256), 0, stream>>>(x, w_gate, w_beta, w_alpha,
      dt_bias, A_log, invn, gate, beta, dec);
  k_mm<<<dim3(8,128), dim3(256), 0, stream>>>(x, btw, x, vbuf, 0);
  k_chunk<<<dim3(B_*H_*N_), dim3(256), 0, stream>>>(x, invn, beta, dec,
      cum, vbuf, wkop);
  k_scan<<<dim3(B_*H_), dim3(1024), 0, stream>>>(x, invn, cum, vbuf, wkop);
  k_o<<<dim3(B_*H_*N_), dim3(256), 0, stream>>>(x, invn, cum, wkop, gate, vbuf);
  k_mm<<<dim3(8,128), dim3(256), 0, stream>>>(vbuf, bto, x, outp, 1);
}